// Round 5
// baseline (255.224 us; speedup 1.0000x reference)
//
#include <hip/hip_runtime.h>
#include <hip/hip_bf16.h>

// ---- problem dims (compile-time) ----
#define DIM     1024
#define DINNER  2048
#define NSTATE  16
#define DTRANK  64
#define DCONV   4
#define BATCH   2
#define SEQ     1024
#define BL      (BATCH*SEQ)     // 2048 rows
#define XDBLW   96              // DTRANK + 2*NSTATE
#define NCHUNK  64
#define TCHUNK  16              // SEQ / NCHUNK
#define KSLICE  16              // split-K factor for G2

typedef __attribute__((ext_vector_type(4))) float  f32x4;
typedef __attribute__((ext_vector_type(8))) short  bf16x8;
typedef unsigned short ushort_t;

__device__ __forceinline__ ushort_t f2bf(float f) {
    union { float f; unsigned int u; } v; v.f = f;
    unsigned int lsb = (v.u >> 16) & 1u;
    v.u += 0x7fffu + lsb;
    return (ushort_t)(v.u >> 16);
}
__device__ __forceinline__ void unpack_bf2(unsigned u, float& lo, float& hi) {
    union { unsigned x; float f; } a, b;
    a.x = u << 16; b.x = u & 0xffff0000u;
    lo = a.f; hi = b.f;
}

typedef __attribute__((address_space(1))) unsigned int gu32_t;
typedef __attribute__((address_space(3))) unsigned int lu32_t;
__device__ __forceinline__ void gload_lds16(const ushort_t* g, ushort_t* l) {
    __builtin_amdgcn_global_load_lds((const gu32_t*)(const void*)g,
                                     (lu32_t*)(void*)l, 16, 0, 0);
}

// ---------------- convert f32 -> bf16 (flat) ----------------
__global__ __launch_bounds__(256) void cvt_f32_bf16(
    const float* __restrict__ src, ushort_t* __restrict__ dst, int n)
{
    int i = (blockIdx.x * 256 + threadIdx.x) * 4;
    if (i >= n) return;
    f32x4 v = *(const f32x4*)(src + i);
    ushort_t r0 = f2bf(v[0]), r1 = f2bf(v[1]), r2 = f2bf(v[2]), r3 = f2bf(v[3]);
    *(uint2*)(dst + i) = make_uint2((unsigned)r0 | ((unsigned)r1 << 16),
                                    (unsigned)r2 | ((unsigned)r3 << 16));
}

// ---------------- transpose f32 (R x C) -> bf16 (C x R), 32x32 tiles ----------------
__global__ __launch_bounds__(256) void transpose_f32_bf16(
    const float* __restrict__ src, ushort_t* __restrict__ dst, int R, int C)
{
    __shared__ float tile[32][33];
    const int tx = threadIdx.x;
    const int ty = threadIdx.y;
    const int r0 = blockIdx.y * 32;
    const int c0 = blockIdx.x * 32;
    #pragma unroll
    for (int i = 0; i < 4; ++i) {
        int r = r0 + ty + i * 8;
        tile[ty + i * 8][tx] = src[(size_t)r * C + c0 + tx];
    }
    __syncthreads();
    #pragma unroll
    for (int i = 0; i < 4; ++i) {
        int c = c0 + ty + i * 8;
        dst[(size_t)c * R + r0 + tx] = f2bf(tile[tx][ty + i * 8]);
    }
}

// ======== m97-style MFMA GEMM: C = A(MxK) * Bt(NxK)^T, full 128-tiles ========
__global__ __launch_bounds__(256) void gemm_lds(
    const ushort_t* __restrict__ A,  int lda,
    const ushort_t* __restrict__ Bt, int ldb,
    int K,
    float* __restrict__ Cf, int ldc)
{
    __shared__ ushort_t As[128 * 32];
    __shared__ ushort_t Bs[128 * 32];

    const int tid  = threadIdx.x;
    const int m0   = blockIdx.y * 128;
    const int n0   = blockIdx.x * 128;
    const int wid  = tid >> 6;
    const int lane = tid & 63;
    const int wm   = (wid >> 1) * 64;
    const int wn   = (wid & 1) * 64;
    const int lr   = lane & 15;
    const int lk   = (lane >> 4) * 8;

    const int c0 = wid * 64 + lane;
    const int c1 = 256 + c0;
    const int r0 = c0 >> 2, f0 = (c0 & 3) * 8;
    const int r1 = c1 >> 2, f1 = (c1 & 3) * 8;
    ushort_t* lA0 = &As[(wid * 64) * 8];
    ushort_t* lA1 = &As[(256 + wid * 64) * 8];
    ushort_t* lB0 = &Bs[(wid * 64) * 8];
    ushort_t* lB1 = &Bs[(256 + wid * 64) * 8];

    f32x4 acc[4][4];
    #pragma unroll
    for (int m = 0; m < 4; ++m)
        #pragma unroll
        for (int n = 0; n < 4; ++n)
            acc[m][n] = (f32x4){0.f, 0.f, 0.f, 0.f};

    for (int k0 = 0; k0 < K; k0 += 32) {
        gload_lds16(A  + (size_t)(m0 + r0) * lda + k0 + f0, lA0);
        gload_lds16(A  + (size_t)(m0 + r1) * lda + k0 + f1, lA1);
        gload_lds16(Bt + (size_t)(n0 + r0) * ldb + k0 + f0, lB0);
        gload_lds16(Bt + (size_t)(n0 + r1) * ldb + k0 + f1, lB1);
        __syncthreads();

        bf16x8 af[4], bfr[4];
        #pragma unroll
        for (int m = 0; m < 4; ++m)
            af[m] = *(const bf16x8*)(&As[(wm + m * 16 + lr) * 32 + lk]);
        #pragma unroll
        for (int n = 0; n < 4; ++n)
            bfr[n] = *(const bf16x8*)(&Bs[(wn + n * 16 + lr) * 32 + lk]);

        #pragma unroll
        for (int m = 0; m < 4; ++m)
            #pragma unroll
            for (int n = 0; n < 4; ++n)
                acc[m][n] = __builtin_amdgcn_mfma_f32_16x16x32_bf16(af[m], bfr[n], acc[m][n], 0, 0, 0);
        __syncthreads();
    }

    const int rbase = (lane >> 4) * 4;
    #pragma unroll
    for (int m = 0; m < 4; ++m) {
        #pragma unroll
        for (int n = 0; n < 4; ++n) {
            int col = n0 + wn + n * 16 + lr;
            #pragma unroll
            for (int r = 0; r < 4; ++r) {
                int row = m0 + wm + m * 16 + rbase + r;
                Cf[(size_t)row * ldc + col] = acc[m][n][r];
            }
        }
    }
}

// ======== G2 split-K: Ppart[ks] = A(128-row tile) * Bt(96xK slice)^T ========
__global__ __launch_bounds__(256) void gemm_n96_splitk(
    const ushort_t* __restrict__ A,    // BL x 2048 (hb)
    const ushort_t* __restrict__ Bt,   // 96 x 2048 (WtXp)
    float* __restrict__ Ppart)         // [KSLICE][BL][96]
{
    __shared__ ushort_t As[128 * 40];
    __shared__ ushort_t Bs[96 * 40];

    const int tid   = threadIdx.x;
    const int ks    = blockIdx.x;
    const int m0    = blockIdx.y * 128;
    const int kbase = ks * (DINNER / KSLICE);
    const int wid   = tid >> 6;
    const int lane  = tid & 63;
    const int wm    = wid * 32;
    const int lr    = lane & 15;
    const int lk    = (lane >> 4) * 8;

    f32x4 acc[2][6];
    #pragma unroll
    for (int m = 0; m < 2; ++m)
        #pragma unroll
        for (int n = 0; n < 6; ++n)
            acc[m][n] = (f32x4){0.f, 0.f, 0.f, 0.f};

    for (int k0 = kbase; k0 < kbase + DINNER / KSLICE; k0 += 32) {
        #pragma unroll
        for (int c = 0; c < 2; ++c) {
            int cid = tid + c * 256;
            int row = cid >> 2, ck = (cid & 3) * 8;
            *(uint4*)(&As[row * 40 + ck]) =
                *(const uint4*)(A + (size_t)(m0 + row) * DINNER + k0 + ck);
        }
        {
            int row = tid >> 2, ck = (tid & 3) * 8;
            *(uint4*)(&Bs[row * 40 + ck]) =
                *(const uint4*)(Bt + (size_t)row * DINNER + k0 + ck);
            if (tid < 128) {
                int cid = 256 + tid;
                int row2 = cid >> 2, ck2 = (cid & 3) * 8;
                *(uint4*)(&Bs[row2 * 40 + ck2]) =
                    *(const uint4*)(Bt + (size_t)row2 * DINNER + k0 + ck2);
            }
        }
        __syncthreads();

        bf16x8 af[2], bfr[6];
        #pragma unroll
        for (int m = 0; m < 2; ++m)
            af[m] = *(const bf16x8*)(&As[(wm + m * 16 + lr) * 40 + lk]);
        #pragma unroll
        for (int n = 0; n < 6; ++n)
            bfr[n] = *(const bf16x8*)(&Bs[(n * 16 + lr) * 40 + lk]);

        #pragma unroll
        for (int m = 0; m < 2; ++m)
            #pragma unroll
            for (int n = 0; n < 6; ++n)
                acc[m][n] = __builtin_amdgcn_mfma_f32_16x16x32_bf16(af[m], bfr[n], acc[m][n], 0, 0, 0);
        __syncthreads();
    }

    const int rbase = (lane >> 4) * 4;
    #pragma unroll
    for (int m = 0; m < 2; ++m) {
        #pragma unroll
        for (int n = 0; n < 6; ++n) {
            int col = n * 16 + lr;
            #pragma unroll
            for (int r = 0; r < 4; ++r) {
                int row = m0 + wm + m * 16 + rbase + r;
                Ppart[((size_t)ks * BL + row) * XDBLW + col] = acc[m][n][r];
            }
        }
    }
}

// reduce split-K partials -> xdbl (f32)
__global__ __launch_bounds__(256) void g2_reduce(
    const float* __restrict__ Ppart, float* __restrict__ xdbl)
{
    int idx = blockIdx.x * 256 + threadIdx.x;     // BL * 24 groups of 4 cols
    int row = idx / 24, cg = (idx % 24) * 4;
    f32x4 s = (f32x4){0.f, 0.f, 0.f, 0.f};
    #pragma unroll
    for (int ks = 0; ks < KSLICE; ++ks)
        s += *(const f32x4*)(Ppart + ((size_t)ks * BL + row) * XDBLW + cg);
    *(f32x4*)(xdbl + (size_t)row * XDBLW + cg) = s;
}

// ---------------- depthwise causal conv(4) + bias + SiLU ----------------
__global__ __launch_bounds__(256) void conv_silu(
    const float* __restrict__ xr,
    const float* __restrict__ convw,
    const float* __restrict__ convb,
    float* __restrict__ hf, ushort_t* __restrict__ hb)
{
    const int d  = blockIdx.x * 256 + threadIdx.x;
    const int bt = blockIdx.y;
    const int t  = bt & (SEQ - 1);

    float acc = convb[d];
    #pragma unroll
    for (int j = 0; j < DCONV; ++j) {
        int tt = t + j - (DCONV - 1);
        if (tt >= 0)
            acc += convw[d * DCONV + j] * xr[(size_t)(bt + j - (DCONV - 1)) * 4096 + d];
    }
    float h = acc / (1.f + expf(-acc));
    hf[(size_t)bt * DINNER + d] = h;
    hb[(size_t)bt * DINNER + d] = f2bf(h);
}

// ================= chunked parallel selective scan (delta fused) =================
// delta[row][d] = softplus(dot(xdbl[row][0:64], WtDt[d][:]) + dtb[d]) computed inline.
__global__ __launch_bounds__(256) void scan_p1(
    const float* __restrict__ hf,
    const float* __restrict__ xdbl,
    const ushort_t* __restrict__ WtDt,   // 2048 x 64 bf16 (dt_proj_w^T)
    const float* __restrict__ dtb,
    const float* __restrict__ Alog,
    float* __restrict__ Pbuf,
    float* __restrict__ Sbuf)
{
    __shared__ float dltS[TCHUNK][DTRANK];   // 4 KB
    const int tid = threadIdx.x;
    const int d  = (blockIdx.x & 7) * 256 + tid;
    const int bc = blockIdx.x >> 3;
    const int b  = bc >> 6;
    const int c  = bc & (NCHUNK - 1);
    const int t0 = c * TCHUNK;
    const size_t row0 = (size_t)(b * SEQ + t0);

    // stage dlt rows (16 x 64 f32), coalesced: 16 threads x 16B per row
    {
        int seg = tid >> 4, off = (tid & 15) * 4;
        *(f32x4*)&dltS[seg][off] = *(const f32x4*)(xdbl + (row0 + seg) * XDBLW + off);
    }
    __syncthreads();

    // W_dt column for this d: 64 contiguous bf16
    float W[DTRANK];
    {
        const ushort_t* wr = WtDt + (size_t)d * DTRANK;
        #pragma unroll
        for (int q = 0; q < 4; ++q) {
            uint4 wv = *(const uint4*)(wr + q * 16);
            unpack_bf2(wv.x, W[q*16+0],  W[q*16+1]);
            unpack_bf2(wv.y, W[q*16+2],  W[q*16+3]);
            unpack_bf2(wv.z, W[q*16+4],  W[q*16+5]);
            unpack_bf2(wv.w, W[q*16+6],  W[q*16+7]);
            uint4 wv2 = *(const uint4*)(wr + q * 16 + 8);
            unpack_bf2(wv2.x, W[q*16+8],  W[q*16+9]);
            unpack_bf2(wv2.y, W[q*16+10], W[q*16+11]);
            unpack_bf2(wv2.z, W[q*16+12], W[q*16+13]);
            unpack_bf2(wv2.w, W[q*16+14], W[q*16+15]);
        }
    }
    const float bi = dtb[d];

    float A[NSTATE];
    #pragma unroll
    for (int q = 0; q < 4; ++q) {
        f32x4 al = *(const f32x4*)(Alog + (size_t)d * NSTATE + q * 4);
        #pragma unroll
        for (int j = 0; j < 4; ++j) A[q * 4 + j] = -expf(al[j]);
    }

    float s[NSTATE], pp[NSTATE];
    #pragma unroll
    for (int n = 0; n < NSTATE; ++n) { s[n] = 0.f; pp[n] = 1.f; }

    for (int tt = 0; tt < TCHUNK; ++tt) {
        const size_t row = row0 + tt;
        float acc = bi;
        #pragma unroll
        for (int q = 0; q < 16; ++q) {
            f32x4 dv = *(const f32x4*)&dltS[tt][q * 4];
            acc = fmaf(dv[0], W[q*4+0], acc);
            acc = fmaf(dv[1], W[q*4+1], acc);
            acc = fmaf(dv[2], W[q*4+2], acc);
            acc = fmaf(dv[3], W[q*4+3], acc);
        }
        float dl = (acc > 20.f) ? acc : log1pf(expf(acc));
        float hv = hf[row * DINNER + d];
        float dlh = dl * hv;
        float Bv[NSTATE];
        #pragma unroll
        for (int q = 0; q < 4; ++q) {
            f32x4 bv = *(const f32x4*)(xdbl + row * XDBLW + DTRANK + q * 4);
            #pragma unroll
            for (int j = 0; j < 4; ++j) Bv[q * 4 + j] = bv[j];
        }
        #pragma unroll
        for (int n = 0; n < NSTATE; ++n) {
            float a = expf(dl * A[n]);
            s[n]  = fmaf(a, s[n], dlh * Bv[n]);
            pp[n] *= a;
        }
    }

    const size_t o = (((size_t)b * NCHUNK + c) * DINNER + d) * NSTATE;
    #pragma unroll
    for (int q = 0; q < 4; ++q) {
        *(f32x4*)(Sbuf + o + q * 4) = (f32x4){s[q*4+0], s[q*4+1], s[q*4+2], s[q*4+3]};
        *(f32x4*)(Pbuf + o + q * 4) = (f32x4){pp[q*4+0], pp[q*4+1], pp[q*4+2], pp[q*4+3]};
    }
}

__global__ __launch_bounds__(256) void scan_p2(
    const float* __restrict__ Pbuf, float* __restrict__ Sbuf)
{
    const int tid = blockIdx.x * 256 + threadIdx.x;
    const int n = tid & 15;
    const int d = (tid >> 4) & (DINNER - 1);
    const int b = tid >> 15;
    const size_t stride = (size_t)DINNER * NSTATE;
    size_t idx = ((size_t)b * NCHUNK * DINNER + d) * NSTATE + n;
    float cin = 0.f;
    for (int c = 0; c < NCHUNK; ++c, idx += stride) {
        float S = Sbuf[idx];
        float P = Pbuf[idx];
        Sbuf[idx] = cin;
        cin = fmaf(P, cin, S);
    }
}

__global__ __launch_bounds__(256) void scan_p3(
    const float* __restrict__ hf,
    const float* __restrict__ xdbl,
    const ushort_t* __restrict__ WtDt,
    const float* __restrict__ dtb,
    const float* __restrict__ xr,      // res at +2048
    const float* __restrict__ Alog,
    const float* __restrict__ Dp,
    const float* __restrict__ Sbuf,
    ushort_t* __restrict__ yb)
{
    __shared__ float dltS[TCHUNK][DTRANK];
    const int tid = threadIdx.x;
    const int d  = (blockIdx.x & 7) * 256 + tid;
    const int bc = blockIdx.x >> 3;
    const int b  = bc >> 6;
    const int c  = bc & (NCHUNK - 1);
    const int t0 = c * TCHUNK;
    const size_t row0 = (size_t)(b * SEQ + t0);

    {
        int seg = tid >> 4, off = (tid & 15) * 4;
        *(f32x4*)&dltS[seg][off] = *(const f32x4*)(xdbl + (row0 + seg) * XDBLW + off);
    }
    __syncthreads();

    float W[DTRANK];
    {
        const ushort_t* wr = WtDt + (size_t)d * DTRANK;
        #pragma unroll
        for (int q = 0; q < 4; ++q) {
            uint4 wv = *(const uint4*)(wr + q * 16);
            unpack_bf2(wv.x, W[q*16+0],  W[q*16+1]);
            unpack_bf2(wv.y, W[q*16+2],  W[q*16+3]);
            unpack_bf2(wv.z, W[q*16+4],  W[q*16+5]);
            unpack_bf2(wv.w, W[q*16+6],  W[q*16+7]);
            uint4 wv2 = *(const uint4*)(wr + q * 16 + 8);
            unpack_bf2(wv2.x, W[q*16+8],  W[q*16+9]);
            unpack_bf2(wv2.y, W[q*16+10], W[q*16+11]);
            unpack_bf2(wv2.z, W[q*16+12], W[q*16+13]);
            unpack_bf2(wv2.w, W[q*16+14], W[q*16+15]);
        }
    }
    const float bi = dtb[d];

    float A[NSTATE];
    #pragma unroll
    for (int q = 0; q < 4; ++q) {
        f32x4 al = *(const f32x4*)(Alog + (size_t)d * NSTATE + q * 4);
        #pragma unroll
        for (int j = 0; j < 4; ++j) A[q * 4 + j] = -expf(al[j]);
    }
    const float Dd = Dp[d];

    float s[NSTATE];
    const size_t o = (((size_t)b * NCHUNK + c) * DINNER + d) * NSTATE;
    #pragma unroll
    for (int q = 0; q < 4; ++q) {
        f32x4 sv = *(const f32x4*)(Sbuf + o + q * 4);
        #pragma unroll
        for (int j = 0; j < 4; ++j) s[q * 4 + j] = sv[j];
    }

    for (int tt = 0; tt < TCHUNK; ++tt) {
        const size_t row = row0 + tt;
        float acc = bi;
        #pragma unroll
        for (int q = 0; q < 16; ++q) {
            f32x4 dv = *(const f32x4*)&dltS[tt][q * 4];
            acc = fmaf(dv[0], W[q*4+0], acc);
            acc = fmaf(dv[1], W[q*4+1], acc);
            acc = fmaf(dv[2], W[q*4+2], acc);
            acc = fmaf(dv[3], W[q*4+3], acc);
        }
        float dl = (acc > 20.f) ? acc : log1pf(expf(acc));
        float hv = hf[row * DINNER + d];
        float rv = xr[row * 4096 + DINNER + d];
        float dlh = dl * hv;
        float Bv[NSTATE], Cv[NSTATE];
        #pragma unroll
        for (int q = 0; q < 4; ++q) {
            f32x4 bv = *(const f32x4*)(xdbl + row * XDBLW + DTRANK + q * 4);
            f32x4 cv = *(const f32x4*)(xdbl + row * XDBLW + DTRANK + NSTATE + q * 4);
            #pragma unroll
            for (int j = 0; j < 4; ++j) { Bv[q*4+j] = bv[j]; Cv[q*4+j] = cv[j]; }
        }
        float y = 0.f;
        #pragma unroll
        for (int n = 0; n < NSTATE; ++n) {
            float a = expf(dl * A[n]);
            s[n] = fmaf(a, s[n], dlh * Bv[n]);
            y = fmaf(s[n], Cv[n], y);
        }
        y = fmaf(hv, Dd, y);
        float sig = 1.f / (1.f + expf(-rv));
        y *= rv * sig;
        yb[row * DINNER + d] = f2bf(y);
    }
}

extern "C" void kernel_launch(void* const* d_in, const int* in_sizes, int n_in,
                              void* d_out, int out_size, void* d_ws, size_t ws_size,
                              hipStream_t stream)
{
    const float* x     = (const float*)d_in[0];
    const float* Win   = (const float*)d_in[1];
    const float* convw = (const float*)d_in[2];
    const float* convb = (const float*)d_in[3];
    const float* Wxp   = (const float*)d_in[4];
    const float* Wdt   = (const float*)d_in[5];
    const float* dtb   = (const float*)d_in[6];
    const float* Alog  = (const float*)d_in[7];
    const float* Dp    = (const float*)d_in[8];
    const float* Wout  = (const float*)d_in[9];
    float* out = (float*)d_out;

    char* base = (char*)d_ws; size_t off = 0;
    auto alloc = [&](size_t bytes) -> char* {
        char* q = base + off;
        off = (off + bytes + 255) & ~(size_t)255;
        return q;
    };
    ushort_t* WtIn  = (ushort_t*)alloc((size_t)4096 * 1024 * 2);
    ushort_t* WtOut = (ushort_t*)alloc((size_t)1024 * 2048 * 2);
    ushort_t* WtXp  = (ushort_t*)alloc((size_t)96   * 2048 * 2);
    ushort_t* WtDt  = (ushort_t*)alloc((size_t)2048 * 64   * 2);
    ushort_t* xb    = (ushort_t*)alloc((size_t)BL * DIM * 2);
    float*    xr    = (float*)   alloc((size_t)BL * 4096 * 4);
    float*    hf    = (float*)   alloc((size_t)BL * DINNER * 4);
    ushort_t* hb    = (ushort_t*)alloc((size_t)BL * DINNER * 2);
    float*    xdbl  = (float*)   alloc((size_t)BL * XDBLW * 4);
    ushort_t* yb    = (ushort_t*)alloc((size_t)BL * DINNER * 2);
    float*    Pbuf  = (float*)   alloc((size_t)BATCH * NCHUNK * DINNER * NSTATE * 4);  // 16 MB
    float*    Sbuf  = (float*)   alloc((size_t)BATCH * NCHUNK * DINNER * NSTATE * 4);
    float*    Ppart = Pbuf;   // G2 split-K partials alias Pbuf (dead before scan_p1)
    (void)ws_size;

    dim3 tb(32, 8);
    transpose_f32_bf16<<<dim3(4096/32, 1024/32), tb, 0, stream>>>(Win,  WtIn,  1024, 4096);
    transpose_f32_bf16<<<dim3(1024/32, 2048/32), tb, 0, stream>>>(Wout, WtOut, 2048, 1024);
    transpose_f32_bf16<<<dim3(96/32,   2048/32), tb, 0, stream>>>(Wxp,  WtXp,  2048, 96);
    transpose_f32_bf16<<<dim3(2048/32, 64/32),   tb, 0, stream>>>(Wdt,  WtDt,  64,   2048);
    cvt_f32_bf16<<<dim3((BL*DIM/4 + 255)/256), 256, 0, stream>>>(x, xb, BL*DIM);

    // G1: xr = x @ in_proj_w   (2048 x 4096, K=1024)
    gemm_lds<<<dim3(4096/128, BL/128), 256, 0, stream>>>(
        xb, DIM, WtIn, DIM, DIM, xr, 2*DINNER);

    conv_silu<<<dim3(DINNER/256, BL), 256, 0, stream>>>(xr, convw, convb, hf, hb);

    // G2: xdbl = h @ x_proj_w  (2048 x 96, K=2048) via split-K + reduce
    gemm_n96_splitk<<<dim3(KSLICE, BL/128), 256, 0, stream>>>(hb, WtXp, Ppart);
    g2_reduce<<<dim3(BL * 24 / 256), 256, 0, stream>>>(Ppart, xdbl);

    // chunked parallel scan with fused delta (dt_proj + softplus inline)
    scan_p1<<<dim3(8 * BATCH * NCHUNK), 256, 0, stream>>>(hf, xdbl, WtDt, dtb, Alog, Pbuf, Sbuf);
    scan_p2<<<dim3(BATCH * DINNER * NSTATE / 256), 256, 0, stream>>>(Pbuf, Sbuf);
    scan_p3<<<dim3(8 * BATCH * NCHUNK), 256, 0, stream>>>(hf, xdbl, WtDt, dtb, xr, Alog, Dp, Sbuf, yb);

    // G4: out = y @ out_proj_w (2048 x 1024, K=2048) -> f32 d_out
    gemm_lds<<<dim3(DIM/128, BL/128), 256, 0, stream>>>(
        yb, DINNER, WtOut, DINNER, DINNER, out, DIM);
}

// Round 6
// 241.440 us; speedup vs baseline: 1.0571x; 1.0571x over previous
//
#include <hip/hip_runtime.h>
#include <hip/hip_bf16.h>

// ---- problem dims (compile-time) ----
#define DIM     1024
#define DINNER  2048
#define NSTATE  16
#define DTRANK  64
#define DCONV   4
#define BATCH   2
#define SEQ     1024
#define BL      (BATCH*SEQ)     // 2048 rows
#define XDBLW   96              // DTRANK + 2*NSTATE
#define NCHUNK  64
#define TCHUNK  16              // SEQ / NCHUNK
#define KSLICE  16              // split-K factor for G2

typedef __attribute__((ext_vector_type(4))) float  f32x4;
typedef __attribute__((ext_vector_type(8))) short  bf16x8;
typedef unsigned short ushort_t;

__device__ __forceinline__ ushort_t f2bf(float f) {
    union { float f; unsigned int u; } v; v.f = f;
    unsigned int lsb = (v.u >> 16) & 1u;
    v.u += 0x7fffu + lsb;
    return (ushort_t)(v.u >> 16);
}

typedef __attribute__((address_space(1))) unsigned int gu32_t;
typedef __attribute__((address_space(3))) unsigned int lu32_t;
__device__ __forceinline__ void gload_lds16(const ushort_t* g, ushort_t* l) {
    __builtin_amdgcn_global_load_lds((const gu32_t*)(const void*)g,
                                     (lu32_t*)(void*)l, 16, 0, 0);
}

// ---------------- convert f32 -> bf16 (flat) ----------------
__global__ __launch_bounds__(256) void cvt_f32_bf16(
    const float* __restrict__ src, ushort_t* __restrict__ dst, int n)
{
    int i = (blockIdx.x * 256 + threadIdx.x) * 4;
    if (i >= n) return;
    f32x4 v = *(const f32x4*)(src + i);
    ushort_t r0 = f2bf(v[0]), r1 = f2bf(v[1]), r2 = f2bf(v[2]), r3 = f2bf(v[3]);
    *(uint2*)(dst + i) = make_uint2((unsigned)r0 | ((unsigned)r1 << 16),
                                    (unsigned)r2 | ((unsigned)r3 << 16));
}

// ---------------- transpose f32 (R x C) -> bf16 (C x R), 32x32 tiles ----------------
__global__ __launch_bounds__(256) void transpose_f32_bf16(
    const float* __restrict__ src, ushort_t* __restrict__ dst, int R, int C)
{
    __shared__ float tile[32][33];
    const int tx = threadIdx.x;
    const int ty = threadIdx.y;
    const int r0 = blockIdx.y * 32;
    const int c0 = blockIdx.x * 32;
    #pragma unroll
    for (int i = 0; i < 4; ++i) {
        int r = r0 + ty + i * 8;
        tile[ty + i * 8][tx] = src[(size_t)r * C + c0 + tx];
    }
    __syncthreads();
    #pragma unroll
    for (int i = 0; i < 4; ++i) {
        int c = c0 + ty + i * 8;
        dst[(size_t)c * R + r0 + tx] = f2bf(tile[tx][ty + i * 8]);
    }
}

// ======== m97-style MFMA GEMM: C = A(MxK) * Bt(NxK)^T, full 128-tiles ========
__global__ __launch_bounds__(256) void gemm_lds(
    const ushort_t* __restrict__ A,  int lda,
    const ushort_t* __restrict__ Bt, int ldb,
    int K,
    float* __restrict__ Cf, int ldc)
{
    __shared__ ushort_t As[128 * 32];
    __shared__ ushort_t Bs[128 * 32];

    const int tid  = threadIdx.x;
    const int m0   = blockIdx.y * 128;
    const int n0   = blockIdx.x * 128;
    const int wid  = tid >> 6;
    const int lane = tid & 63;
    const int wm   = (wid >> 1) * 64;
    const int wn   = (wid & 1) * 64;
    const int lr   = lane & 15;
    const int lk   = (lane >> 4) * 8;

    const int c0 = wid * 64 + lane;
    const int c1 = 256 + c0;
    const int r0 = c0 >> 2, f0 = (c0 & 3) * 8;
    const int r1 = c1 >> 2, f1 = (c1 & 3) * 8;
    ushort_t* lA0 = &As[(wid * 64) * 8];
    ushort_t* lA1 = &As[(256 + wid * 64) * 8];
    ushort_t* lB0 = &Bs[(wid * 64) * 8];
    ushort_t* lB1 = &Bs[(256 + wid * 64) * 8];

    f32x4 acc[4][4];
    #pragma unroll
    for (int m = 0; m < 4; ++m)
        #pragma unroll
        for (int n = 0; n < 4; ++n)
            acc[m][n] = (f32x4){0.f, 0.f, 0.f, 0.f};

    for (int k0 = 0; k0 < K; k0 += 32) {
        gload_lds16(A  + (size_t)(m0 + r0) * lda + k0 + f0, lA0);
        gload_lds16(A  + (size_t)(m0 + r1) * lda + k0 + f1, lA1);
        gload_lds16(Bt + (size_t)(n0 + r0) * ldb + k0 + f0, lB0);
        gload_lds16(Bt + (size_t)(n0 + r1) * ldb + k0 + f1, lB1);
        __syncthreads();

        bf16x8 af[4], bfr[4];
        #pragma unroll
        for (int m = 0; m < 4; ++m)
            af[m] = *(const bf16x8*)(&As[(wm + m * 16 + lr) * 32 + lk]);
        #pragma unroll
        for (int n = 0; n < 4; ++n)
            bfr[n] = *(const bf16x8*)(&Bs[(wn + n * 16 + lr) * 32 + lk]);

        #pragma unroll
        for (int m = 0; m < 4; ++m)
            #pragma unroll
            for (int n = 0; n < 4; ++n)
                acc[m][n] = __builtin_amdgcn_mfma_f32_16x16x32_bf16(af[m], bfr[n], acc[m][n], 0, 0, 0);
        __syncthreads();
    }

    const int rbase = (lane >> 4) * 4;
    #pragma unroll
    for (int m = 0; m < 4; ++m) {
        #pragma unroll
        for (int n = 0; n < 4; ++n) {
            int col = n0 + wn + n * 16 + lr;
            #pragma unroll
            for (int r = 0; r < 4; ++r) {
                int row = m0 + wm + m * 16 + rbase + r;
                Cf[(size_t)row * ldc + col] = acc[m][n][r];
            }
        }
    }
}

// ======== G2 split-K: Ppart[ks] = A(128-row tile) * Bt(96xK slice)^T ========
__global__ __launch_bounds__(256) void gemm_n96_splitk(
    const ushort_t* __restrict__ A,    // BL x 2048 (hb)
    const ushort_t* __restrict__ Bt,   // 96 x 2048 (WtXp)
    float* __restrict__ Ppart)         // [KSLICE][BL][96]
{
    __shared__ ushort_t As[128 * 40];
    __shared__ ushort_t Bs[96 * 40];

    const int tid   = threadIdx.x;
    const int ks    = blockIdx.x;
    const int m0    = blockIdx.y * 128;
    const int kbase = ks * (DINNER / KSLICE);
    const int wid   = tid >> 6;
    const int lane  = tid & 63;
    const int wm    = wid * 32;
    const int lr    = lane & 15;
    const int lk    = (lane >> 4) * 8;

    f32x4 acc[2][6];
    #pragma unroll
    for (int m = 0; m < 2; ++m)
        #pragma unroll
        for (int n = 0; n < 6; ++n)
            acc[m][n] = (f32x4){0.f, 0.f, 0.f, 0.f};

    for (int k0 = kbase; k0 < kbase + DINNER / KSLICE; k0 += 32) {
        #pragma unroll
        for (int c = 0; c < 2; ++c) {
            int cid = tid + c * 256;
            int row = cid >> 2, ck = (cid & 3) * 8;
            *(uint4*)(&As[row * 40 + ck]) =
                *(const uint4*)(A + (size_t)(m0 + row) * DINNER + k0 + ck);
        }
        {
            int row = tid >> 2, ck = (tid & 3) * 8;
            *(uint4*)(&Bs[row * 40 + ck]) =
                *(const uint4*)(Bt + (size_t)row * DINNER + k0 + ck);
            if (tid < 128) {
                int cid = 256 + tid;
                int row2 = cid >> 2, ck2 = (cid & 3) * 8;
                *(uint4*)(&Bs[row2 * 40 + ck2]) =
                    *(const uint4*)(Bt + (size_t)row2 * DINNER + k0 + ck2);
            }
        }
        __syncthreads();

        bf16x8 af[2], bfr[6];
        #pragma unroll
        for (int m = 0; m < 2; ++m)
            af[m] = *(const bf16x8*)(&As[(wm + m * 16 + lr) * 40 + lk]);
        #pragma unroll
        for (int n = 0; n < 6; ++n)
            bfr[n] = *(const bf16x8*)(&Bs[(n * 16 + lr) * 40 + lk]);

        #pragma unroll
        for (int m = 0; m < 2; ++m)
            #pragma unroll
            for (int n = 0; n < 6; ++n)
                acc[m][n] = __builtin_amdgcn_mfma_f32_16x16x32_bf16(af[m], bfr[n], acc[m][n], 0, 0, 0);
        __syncthreads();
    }

    const int rbase = (lane >> 4) * 4;
    #pragma unroll
    for (int m = 0; m < 2; ++m) {
        #pragma unroll
        for (int n = 0; n < 6; ++n) {
            int col = n * 16 + lr;
            #pragma unroll
            for (int r = 0; r < 4; ++r) {
                int row = m0 + wm + m * 16 + rbase + r;
                Ppart[((size_t)ks * BL + row) * XDBLW + col] = acc[m][n][r];
            }
        }
    }
}

// reduce split-K partials -> xdbl (f32)
__global__ __launch_bounds__(256) void g2_reduce(
    const float* __restrict__ Ppart, float* __restrict__ xdbl)
{
    int idx = blockIdx.x * 256 + threadIdx.x;
    int row = idx / 24, cg = (idx % 24) * 4;
    f32x4 s = (f32x4){0.f, 0.f, 0.f, 0.f};
    #pragma unroll
    for (int ks = 0; ks < KSLICE; ++ks)
        s += *(const f32x4*)(Ppart + ((size_t)ks * BL + row) * XDBLW + cg);
    *(f32x4*)(xdbl + (size_t)row * XDBLW + cg) = s;
}

// ======== delta = softplus(dlt @ Wdt + dtb) — VALU, spill-free ========
// Wdt is the ORIGINAL (64 x 2048) f32 k-major input. Block: 4 rows x 2048 d.
// Thread: 4 rows x 8 d (d = tid + j*256). 32 accumulators, coalesced W loads.
__global__ __launch_bounds__(256) void delta_kernel(
    const float* __restrict__ xdbl,   // BL x 96, dlt = cols [0,64)
    const float* __restrict__ Wdt,    // 64 x 2048 f32
    const float* __restrict__ dtb,    // 2048
    float* __restrict__ delta)        // BL x 2048
{
    __shared__ float dltS[4][DTRANK];  // 1 KB
    const int tid = threadIdx.x;
    const int r0  = blockIdx.x * 4;

    if (tid < 64) {
        int r = tid >> 4, off = (tid & 15) * 4;
        *(f32x4*)&dltS[r][off] = *(const f32x4*)(xdbl + (size_t)(r0 + r) * XDBLW + off);
    }
    __syncthreads();

    float acc0[8], acc1[8], acc2[8], acc3[8];
    #pragma unroll
    for (int j = 0; j < 8; ++j) {
        float bj = dtb[tid + j * 256];
        acc0[j] = bj; acc1[j] = bj; acc2[j] = bj; acc3[j] = bj;
    }

    #pragma unroll 4
    for (int kc = 0; kc < 16; ++kc) {
        f32x4 dv0 = *(const f32x4*)&dltS[0][kc * 4];
        f32x4 dv1 = *(const f32x4*)&dltS[1][kc * 4];
        f32x4 dv2 = *(const f32x4*)&dltS[2][kc * 4];
        f32x4 dv3 = *(const f32x4*)&dltS[3][kc * 4];
        #pragma unroll
        for (int kk = 0; kk < 4; ++kk) {
            const float* wrow = Wdt + (size_t)(kc * 4 + kk) * DINNER + tid;
            #pragma unroll
            for (int j = 0; j < 8; ++j) {
                float w = wrow[j * 256];
                acc0[j] = fmaf(dv0[kk], w, acc0[j]);
                acc1[j] = fmaf(dv1[kk], w, acc1[j]);
                acc2[j] = fmaf(dv2[kk], w, acc2[j]);
                acc3[j] = fmaf(dv3[kk], w, acc3[j]);
            }
        }
    }

    #pragma unroll
    for (int j = 0; j < 8; ++j) {
        int d = tid + j * 256;
        float v0 = acc0[j], v1 = acc1[j], v2 = acc2[j], v3 = acc3[j];
        v0 = (v0 > 20.f) ? v0 : log1pf(expf(v0));
        v1 = (v1 > 20.f) ? v1 : log1pf(expf(v1));
        v2 = (v2 > 20.f) ? v2 : log1pf(expf(v2));
        v3 = (v3 > 20.f) ? v3 : log1pf(expf(v3));
        delta[(size_t)(r0 + 0) * DINNER + d] = v0;
        delta[(size_t)(r0 + 1) * DINNER + d] = v1;
        delta[(size_t)(r0 + 2) * DINNER + d] = v2;
        delta[(size_t)(r0 + 3) * DINNER + d] = v3;
    }
}

// ---------------- depthwise causal conv(4) + bias + SiLU ----------------
__global__ __launch_bounds__(256) void conv_silu(
    const float* __restrict__ xr,
    const float* __restrict__ convw,
    const float* __restrict__ convb,
    float* __restrict__ hf, ushort_t* __restrict__ hb)
{
    const int d  = blockIdx.x * 256 + threadIdx.x;
    const int bt = blockIdx.y;
    const int t  = bt & (SEQ - 1);

    float acc = convb[d];
    #pragma unroll
    for (int j = 0; j < DCONV; ++j) {
        int tt = t + j - (DCONV - 1);
        if (tt >= 0)
            acc += convw[d * DCONV + j] * xr[(size_t)(bt + j - (DCONV - 1)) * 4096 + d];
    }
    float h = acc / (1.f + expf(-acc));
    hf[(size_t)bt * DINNER + d] = h;
    hb[(size_t)bt * DINNER + d] = f2bf(h);
}

// ================= chunked parallel selective scan =================
__global__ __launch_bounds__(256) void scan_p1(
    const float* __restrict__ delta,
    const float* __restrict__ hf,
    const float* __restrict__ xdbl,
    const float* __restrict__ Alog,
    float* __restrict__ Pbuf,
    float* __restrict__ Sbuf)
{
    const int d  = (blockIdx.x & 7) * 256 + threadIdx.x;
    const int bc = blockIdx.x >> 3;
    const int b  = bc >> 6;
    const int c  = bc & (NCHUNK - 1);
    const int t0 = c * TCHUNK;

    float A[NSTATE];
    #pragma unroll
    for (int q = 0; q < 4; ++q) {
        f32x4 al = *(const f32x4*)(Alog + (size_t)d * NSTATE + q * 4);
        #pragma unroll
        for (int j = 0; j < 4; ++j) A[q * 4 + j] = -expf(al[j]);
    }

    float s[NSTATE], pp[NSTATE];
    #pragma unroll
    for (int n = 0; n < NSTATE; ++n) { s[n] = 0.f; pp[n] = 1.f; }

    for (int tt = 0; tt < TCHUNK; ++tt) {
        const size_t row = (size_t)(b * SEQ + t0 + tt);
        float dl = delta[row * DINNER + d];
        float hv = hf[row * DINNER + d];
        float dlh = dl * hv;
        float Bv[NSTATE];
        #pragma unroll
        for (int q = 0; q < 4; ++q) {
            f32x4 bv = *(const f32x4*)(xdbl + row * XDBLW + DTRANK + q * 4);
            #pragma unroll
            for (int j = 0; j < 4; ++j) Bv[q * 4 + j] = bv[j];
        }
        #pragma unroll
        for (int n = 0; n < NSTATE; ++n) {
            float a = expf(dl * A[n]);
            s[n]  = fmaf(a, s[n], dlh * Bv[n]);
            pp[n] *= a;
        }
    }

    const size_t o = (((size_t)b * NCHUNK + c) * DINNER + d) * NSTATE;
    #pragma unroll
    for (int q = 0; q < 4; ++q) {
        *(f32x4*)(Sbuf + o + q * 4) = (f32x4){s[q*4+0], s[q*4+1], s[q*4+2], s[q*4+3]};
        *(f32x4*)(Pbuf + o + q * 4) = (f32x4){pp[q*4+0], pp[q*4+1], pp[q*4+2], pp[q*4+3]};
    }
}

__global__ __launch_bounds__(256) void scan_p2(
    const float* __restrict__ Pbuf, float* __restrict__ Sbuf)
{
    const int tid = blockIdx.x * 256 + threadIdx.x;
    const int n = tid & 15;
    const int d = (tid >> 4) & (DINNER - 1);
    const int b = tid >> 15;
    const size_t stride = (size_t)DINNER * NSTATE;
    size_t idx = ((size_t)b * NCHUNK * DINNER + d) * NSTATE + n;
    float cin = 0.f;
    for (int c = 0; c < NCHUNK; ++c, idx += stride) {
        float S = Sbuf[idx];
        float P = Pbuf[idx];
        Sbuf[idx] = cin;
        cin = fmaf(P, cin, S);
    }
}

__global__ __launch_bounds__(256) void scan_p3(
    const float* __restrict__ delta,
    const float* __restrict__ hf,
    const float* __restrict__ xdbl,
    const float* __restrict__ xr,      // res at +2048
    const float* __restrict__ Alog,
    const float* __restrict__ Dp,
    const float* __restrict__ Sbuf,
    ushort_t* __restrict__ yb)
{
    const int d  = (blockIdx.x & 7) * 256 + threadIdx.x;
    const int bc = blockIdx.x >> 3;
    const int b  = bc >> 6;
    const int c  = bc & (NCHUNK - 1);
    const int t0 = c * TCHUNK;

    float A[NSTATE];
    #pragma unroll
    for (int q = 0; q < 4; ++q) {
        f32x4 al = *(const f32x4*)(Alog + (size_t)d * NSTATE + q * 4);
        #pragma unroll
        for (int j = 0; j < 4; ++j) A[q * 4 + j] = -expf(al[j]);
    }
    const float Dd = Dp[d];

    float s[NSTATE];
    const size_t o = (((size_t)b * NCHUNK + c) * DINNER + d) * NSTATE;
    #pragma unroll
    for (int q = 0; q < 4; ++q) {
        f32x4 sv = *(const f32x4*)(Sbuf + o + q * 4);
        #pragma unroll
        for (int j = 0; j < 4; ++j) s[q * 4 + j] = sv[j];
    }

    for (int tt = 0; tt < TCHUNK; ++tt) {
        const size_t row = (size_t)(b * SEQ + t0 + tt);
        float dl = delta[row * DINNER + d];
        float hv = hf[row * DINNER + d];
        float rv = xr[row * 4096 + DINNER + d];
        float dlh = dl * hv;
        float Bv[NSTATE], Cv[NSTATE];
        #pragma unroll
        for (int q = 0; q < 4; ++q) {
            f32x4 bv = *(const f32x4*)(xdbl + row * XDBLW + DTRANK + q * 4);
            f32x4 cv = *(const f32x4*)(xdbl + row * XDBLW + DTRANK + NSTATE + q * 4);
            #pragma unroll
            for (int j = 0; j < 4; ++j) { Bv[q*4+j] = bv[j]; Cv[q*4+j] = cv[j]; }
        }
        float y = 0.f;
        #pragma unroll
        for (int n = 0; n < NSTATE; ++n) {
            float a = expf(dl * A[n]);
            s[n] = fmaf(a, s[n], dlh * Bv[n]);
            y = fmaf(s[n], Cv[n], y);
        }
        y = fmaf(hv, Dd, y);
        float sig = 1.f / (1.f + expf(-rv));
        y *= rv * sig;
        yb[row * DINNER + d] = f2bf(y);
    }
}

extern "C" void kernel_launch(void* const* d_in, const int* in_sizes, int n_in,
                              void* d_out, int out_size, void* d_ws, size_t ws_size,
                              hipStream_t stream)
{
    const float* x     = (const float*)d_in[0];
    const float* Win   = (const float*)d_in[1];
    const float* convw = (const float*)d_in[2];
    const float* convb = (const float*)d_in[3];
    const float* Wxp   = (const float*)d_in[4];
    const float* Wdt   = (const float*)d_in[5];   // 64 x 2048 f32 (used directly)
    const float* dtb   = (const float*)d_in[6];
    const float* Alog  = (const float*)d_in[7];
    const float* Dp    = (const float*)d_in[8];
    const float* Wout  = (const float*)d_in[9];
    float* out = (float*)d_out;

    char* base = (char*)d_ws; size_t off = 0;
    auto alloc = [&](size_t bytes) -> char* {
        char* q = base + off;
        off = (off + bytes + 255) & ~(size_t)255;
        return q;
    };
    ushort_t* WtIn  = (ushort_t*)alloc((size_t)4096 * 1024 * 2);
    ushort_t* WtOut = (ushort_t*)alloc((size_t)1024 * 2048 * 2);
    ushort_t* WtXp  = (ushort_t*)alloc((size_t)96   * 2048 * 2);
    ushort_t* xb    = (ushort_t*)alloc((size_t)BL * DIM * 2);
    float*    xr    = (float*)   alloc((size_t)BL * 4096 * 4);
    float*    hf    = (float*)   alloc((size_t)BL * DINNER * 4);
    ushort_t* hb    = (ushort_t*)alloc((size_t)BL * DINNER * 2);
    float*    xdbl  = (float*)   alloc((size_t)BL * XDBLW * 4);
    float*    delta = (float*)   alloc((size_t)BL * DINNER * 4);
    ushort_t* yb    = (ushort_t*)alloc((size_t)BL * DINNER * 2);
    float*    Pbuf  = (float*)   alloc((size_t)BATCH * NCHUNK * DINNER * NSTATE * 4);
    float*    Sbuf  = (float*)   alloc((size_t)BATCH * NCHUNK * DINNER * NSTATE * 4);
    float*    Ppart = Pbuf;   // G2 split-K partials alias Pbuf (dead before scan_p1)
    (void)ws_size;

    dim3 tb(32, 8);
    transpose_f32_bf16<<<dim3(4096/32, 1024/32), tb, 0, stream>>>(Win,  WtIn,  1024, 4096);
    transpose_f32_bf16<<<dim3(1024/32, 2048/32), tb, 0, stream>>>(Wout, WtOut, 2048, 1024);
    transpose_f32_bf16<<<dim3(96/32,   2048/32), tb, 0, stream>>>(Wxp,  WtXp,  2048, 96);
    cvt_f32_bf16<<<dim3((BL*DIM/4 + 255)/256), 256, 0, stream>>>(x, xb, BL*DIM);

    // G1: xr = x @ in_proj_w   (2048 x 4096, K=1024)
    gemm_lds<<<dim3(4096/128, BL/128), 256, 0, stream>>>(
        xb, DIM, WtIn, DIM, DIM, xr, 2*DINNER);

    conv_silu<<<dim3(DINNER/256, BL), 256, 0, stream>>>(xr, convw, convb, hf, hb);

    // G2: xdbl = h @ x_proj_w  (2048 x 96, K=2048) via split-K + reduce
    gemm_n96_splitk<<<dim3(KSLICE, BL/128), 256, 0, stream>>>(hb, WtXp, Ppart);
    g2_reduce<<<dim3(BL * 24 / 256), 256, 0, stream>>>(Ppart, xdbl);

    // delta = softplus(dlt @ dt_proj_w + dt_b) — VALU kernel, original W layout
    delta_kernel<<<dim3(BL / 4), 256, 0, stream>>>(xdbl, Wdt, dtb, delta);

    // chunked parallel scan
    scan_p1<<<dim3(8 * BATCH * NCHUNK), 256, 0, stream>>>(delta, hf, xdbl, Alog, Pbuf, Sbuf);
    scan_p2<<<dim3(BATCH * DINNER * NSTATE / 256), 256, 0, stream>>>(Pbuf, Sbuf);
    scan_p3<<<dim3(8 * BATCH * NCHUNK), 256, 0, stream>>>(delta, hf, xdbl, xr, Alog, Dp, Sbuf, yb);

    // G4: out = y @ out_proj_w (2048 x 1024, K=2048) -> f32 d_out
    gemm_lds<<<dim3(DIM/128, BL/128), 256, 0, stream>>>(
        yb, DINNER, WtOut, DINNER, DINNER, out, DIM);
}